// Round 4
// baseline (321.381 us; speedup 1.0000x reference)
//
#include <hip/hip_runtime.h>

typedef __attribute__((ext_vector_type(8))) short short8v;
typedef __attribute__((ext_vector_type(4))) float f32x4;

// ws layout:
//   ushort [0 .. 327679]  : W bf16 panels [part(2)][gate(80)][k(2048)]
//   float  [163840 ..]    : constants
#define WSL   163840           // loss column (80 f32)
#define WSC1  (WSL+80)         // folded gate-1 constants (80)
#define WSC2  (WSC1+80)        // folded gate-2 constants (80)
#define WSPF  (WSC2+80)        // poly factor scalar

__device__ __forceinline__ float fsig(float x){ return 1.0f/(1.0f + __expf(-x)); }
__device__ __forceinline__ float ftanh(float x){ float e = __expf(2.0f*x); return 1.0f - 2.0f/(e+1.0f); }
__device__ __forceinline__ unsigned short f2bf_rne(float f){
  unsigned u = __float_as_uint(f);
  u += 0x7fffu + ((u >> 16) & 1u);
  return (unsigned short)(u >> 16);
}
// pack two floats -> two bf16 (round-half-up; cheap, error negligible here)
__device__ __forceinline__ unsigned pack2bf(float lo, float hi){
  unsigned a = __float_as_uint(lo) + 0x8000u;
  unsigned b = __float_as_uint(hi) + 0x8000u;
  return (a >> 16) | (b & 0xFFFF0000u);
}

__global__ __launch_bounds__(256,1) void prep_kernel(
    const float* __restrict__ W_ih1, const float* __restrict__ b_ih1,
    const float* __restrict__ W_hh1, const float* __restrict__ b_hh1,
    const float* __restrict__ b_ih2, const float* __restrict__ W_hh2,
    const float* __restrict__ b_hh2, const float* __restrict__ h1_0,
    const float* __restrict__ h2_0, const float* __restrict__ alpha_raw,
    const int* __restrict__ t, float* __restrict__ ws)
{
  const int b = blockIdx.x;            // 160 blocks: gate(80) x part(2)
  const int gate = b >> 1, part = b & 1;
  const float* src = W_ih1 + (size_t)gate*4097 + (part ? 2049 : 0);
  unsigned short* dst = (unsigned short*)ws + (size_t)part*163840 + (size_t)gate*2048;
  for (int k = threadIdx.x; k < 2048; k += 256) dst[k] = f2bf_rne(src[k]);
  if (b == 0) {
    const int tix = threadIdx.x;
    if (tix < 80) {
      float s = b_ih1[tix] + b_hh1[tix];
      for (int j = 0; j < 20; ++j) s += W_hh1[tix*20+j]*h1_0[j];
      ws[WSC1+tix] = s;
    } else if (tix < 160) {
      const int kk = tix - 80;
      float s = b_ih2[kk] + b_hh2[kk];
      for (int j = 0; j < 20; ++j) s += W_hh2[kk*20+j]*h2_0[j];
      ws[WSC2+kk] = s;
    } else if (tix < 240) {
      const int kk = tix - 160;
      ws[WSL+kk] = W_ih1[(size_t)kk*4097 + 2048];   // loss column
    } else if (tix == 240) {
      const float tv = (float)(*t);
      float pf = 0.f, term = 1.f;
      for (int j = 0; j < 3; ++j) {
        float a = alpha_raw[j];
        float sp = (a > 20.f) ? a : log1pf(__expf(a));
        pf += sp*term; term *= tv;                   // t^0 == 1 even at t=0
      }
      pf *= powf(0.99f, tv);
      ws[WSPF] = pf;
    }
  }
}

// 256 blocks x 512 thr. Block = 16 rows. 8 waves = part(2) x k-slice(4 x 512).
// MFMA 16x16x32 bf16; per wave 5 N-tiles (80 gates of its part).
// A frag: lane holds x[r0+(l&15)][k0+(l>>4)*8 + j], j=0..7 (8 consecutive f32 -> bf16).
// B frag: lane holds W[tile*16+(l&15)][k0+(l>>4)*8 + j]  (bf16 panel, row-major).
// C/D:    acc[t][r] = C[row=(l>>4)*4+r][col=tile*16+(l&15)]   (m89-verified layout).
__global__ __launch_bounds__(512,2) void main_kernel(
    const float* __restrict__ x, const float* __restrict__ loss,
    const float* __restrict__ grad, const float* __restrict__ W_ih2,
    const float* __restrict__ W_out, const float* __restrict__ b_out,
    const float* __restrict__ c1_0, const float* __restrict__ c2_0,
    const float* __restrict__ ws, float* __restrict__ out)
{
  __shared__ float pbuf[2][16][168];   // f32 gate partials, atomicAdd combine
  __shared__ float wih2[1600];
  __shared__ float g1[16][80];
  __shared__ float h1s[16][20], h2s[16][20];
  __shared__ float c10[20], c20[20];
  __shared__ float invX[16], invG[16], lscA[16], axv[16];
  __shared__ unsigned smaxX[16], smaxG[16];

  const int tid  = threadIdx.x;
  const int w    = tid >> 6, lane = tid & 63;
  const int part = w >> 2, wk = w & 3;
  const int m    = lane & 15, kg = lane >> 4;
  const int r0   = blockIdx.x * 16;

  for (int i = tid; i < 2*16*168; i += 512) (&pbuf[0][0][0])[i] = 0.f;
  for (int i = tid; i < 1600; i += 512) wih2[i] = W_ih2[i];
  if (tid < 20) { c10[tid] = c1_0[tid]; c20[tid] = c2_0[tid]; }
  if (tid < 16) { smaxX[tid] = 0u; smaxG[tid] = 0u; }
  __syncthreads();

  const float* Ap = (part ? grad : x) + (size_t)(r0 + m)*2048 + wk*512 + kg*8;
  const unsigned short* Bp = (const unsigned short*)ws + (size_t)part*163840
                           + (size_t)m*2048 + wk*512 + kg*8;

  f32x4 acc[5];
  #pragma unroll
  for (int t = 0; t < 5; ++t) acc[t] = (f32x4){0.f,0.f,0.f,0.f};
  float vm = 0.f;

  #pragma unroll 2
  for (int ks = 0; ks < 16; ++ks) {
    const float4 a0 = *(const float4*)(Ap + ks*32);
    const float4 a1 = *(const float4*)(Ap + ks*32 + 4);
    vm = fmaxf(vm, fmaxf(fmaxf(fabsf(a0.x),fabsf(a0.y)), fmaxf(fabsf(a0.z),fabsf(a0.w))));
    vm = fmaxf(vm, fmaxf(fmaxf(fabsf(a1.x),fabsf(a1.y)), fmaxf(fabsf(a1.z),fabsf(a1.w))));
    union { unsigned u[4]; short8v v; } A_;
    A_.u[0] = pack2bf(a0.x, a0.y);
    A_.u[1] = pack2bf(a0.z, a0.w);
    A_.u[2] = pack2bf(a1.x, a1.y);
    A_.u[3] = pack2bf(a1.z, a1.w);
    const short8v af = A_.v;
    #pragma unroll
    for (int t = 0; t < 5; ++t) {
      const short8v bf = *(const short8v*)(Bp + (size_t)t*32768 + ks*32);
      acc[t] = __builtin_amdgcn_mfma_f32_16x16x32_bf16(af, bf, acc[t], 0, 0, 0);
    }
  }

  // row-max reduce across the 4 k-groups holding the same row (xor 16, 32)
  vm = fmaxf(vm, __shfl_xor(vm, 16));
  vm = fmaxf(vm, __shfl_xor(vm, 32));
  if (lane < 16) atomicMax(part ? &smaxG[m] : &smaxX[m], __float_as_uint(vm));

  #pragma unroll
  for (int t = 0; t < 5; ++t)
    #pragma unroll
    for (int r = 0; r < 4; ++r)
      atomicAdd(&pbuf[part][kg*4 + r][t*16 + m], acc[t][r]);
  __syncthreads();

  if (tid < 16) {
    float ax = __uint_as_float(smaxX[tid]); ax = (ax > 0.f) ? ax : 1.0f;
    axv[tid] = ax; invX[tid] = 1.0f/ax;
    float ag = __uint_as_float(smaxG[tid]); ag = (ag > 0.f) ? ag : 1.0f;
    invG[tid] = 1.0f/ag;
    float l  = loss[r0 + tid];
    float al = fabsf(l); al = (al > 0.f) ? al : 1.0f;
    lscA[tid] = l / al;
  }
  __syncthreads();

  for (int idx = tid; idx < 1280; idx += 512) {      // gates 1 (16 rows x 80)
    const int r = idx / 80, k2 = idx - r*80;
    g1[r][k2] = pbuf[0][r][k2]*invX[r] + pbuf[1][r][k2]*invG[r]
              + ws[WSL+k2]*lscA[r] + ws[WSC1+k2];
  }
  __syncthreads();

  if (tid < 320) {                                   // cell 1 (16 rows x 20)
    const int r = tid / 20, j = tid - r*20;
    const float gi = g1[r][j], gf = g1[r][20+j], gc = g1[r][40+j], go = g1[r][60+j];
    const float c1 = fsig(gf)*c10[j] + fsig(gi)*ftanh(gc);
    h1s[r][j] = fsig(go)*ftanh(c1);
  }
  __syncthreads();

  for (int idx = tid; idx < 1280; idx += 512) {      // gates 2
    const int r = idx / 80, k2 = idx - r*80;
    float s = ws[WSC2+k2];
    #pragma unroll
    for (int j = 0; j < 20; ++j) s += wih2[k2*20+j]*h1s[r][j];
    g1[r][k2] = s;
  }
  __syncthreads();

  if (tid < 320) {                                   // cell 2
    const int r = tid / 20, j = tid - r*20;
    const float gi = g1[r][j], gf = g1[r][20+j], gc = g1[r][40+j], go = g1[r][60+j];
    const float c2v = fsig(gf)*c20[j] + fsig(gi)*ftanh(gc);
    h2s[r][j] = fsig(go)*ftanh(c2v);
  }
  __syncthreads();

  const float pf = ws[WSPF];                         // output GEMV + tanh + scale
  #pragma unroll
  for (int q = 0; q < 4; ++q) {
    const int d = q*512 + tid;
    const float4* wr = (const float4*)(W_out + (size_t)d*20);
    const float4 w0 = wr[0], w1 = wr[1], w2 = wr[2], w3 = wr[3], w4 = wr[4];
    const float bo = b_out[d];
    #pragma unroll
    for (int r = 0; r < 16; ++r) {
      const float4* hp = (const float4*)&h2s[r][0];
      const float4 h0 = hp[0], h1v = hp[1], h2v = hp[2], h3v = hp[3], h4v = hp[4];
      float v = bo;
      v += w0.x*h0.x  + w0.y*h0.y  + w0.z*h0.z  + w0.w*h0.w;
      v += w1.x*h1v.x + w1.y*h1v.y + w1.z*h1v.z + w1.w*h1v.w;
      v += w2.x*h2v.x + w2.y*h2v.y + w2.z*h2v.z + w2.w*h2v.w;
      v += w3.x*h3v.x + w3.y*h3v.y + w3.z*h3v.z + w3.w*h3v.w;
      v += w4.x*h4v.x + w4.y*h4v.y + w4.z*h4v.z + w4.w*h4v.w;
      out[(size_t)(r0+r)*2048 + d] = pf * axv[r] * ftanh(v);
    }
  }
}

extern "C" void kernel_launch(void* const* d_in, const int* in_sizes, int n_in,
                              void* d_out, int out_size, void* d_ws, size_t ws_size,
                              hipStream_t stream)
{
  const float* x      = (const float*)d_in[0];
  const float* loss   = (const float*)d_in[1];
  const float* grad   = (const float*)d_in[2];
  const float* W_ih1  = (const float*)d_in[3];
  const float* b_ih1  = (const float*)d_in[4];
  const float* W_hh1  = (const float*)d_in[5];
  const float* b_hh1  = (const float*)d_in[6];
  const float* W_ih2  = (const float*)d_in[7];
  const float* b_ih2  = (const float*)d_in[8];
  const float* W_hh2  = (const float*)d_in[9];
  const float* b_hh2  = (const float*)d_in[10];
  const float* W_out  = (const float*)d_in[11];
  const float* b_out  = (const float*)d_in[12];
  const float* h1_0   = (const float*)d_in[13];
  const float* c1_0   = (const float*)d_in[14];
  const float* h2_0   = (const float*)d_in[15];
  const float* c2_0   = (const float*)d_in[16];
  const float* alpha  = (const float*)d_in[17];
  const int*   t      = (const int*)d_in[18];
  float* ws  = (float*)d_ws;
  float* out = (float*)d_out;

  hipLaunchKernelGGL(prep_kernel, dim3(160), dim3(256), 0, stream,
                     W_ih1, b_ih1, W_hh1, b_hh1, b_ih2, W_hh2, b_hh2,
                     h1_0, h2_0, alpha, t, ws);
  hipLaunchKernelGGL(main_kernel, dim3(256), dim3(512), 0, stream,
                     x, loss, grad, W_ih2, W_out, b_out, c1_0, c2_0, ws, out);
}